// Round 7
// baseline (706.071 us; speedup 1.0000x reference)
//
#include <hip/hip_runtime.h>
#include <math.h>

// EnvAwareRouter: B=524288, C=13, T=24, H=64, E=8, K=3, tau=1, eps=1e-10
// Output: concat[ mask(B,E), probs(B,E) ] f32
//
// R7 = R6 two-phase structure + guaranteed packed-fp32 math in phase 1.
//  - fc1/fc2 MACs via inline-asm v_pk_fma_f32 (the 157.3 TF packed path):
//    weights as wave-uniform 64-bit SGPR-pair operands (s_load, 1 sgpr read
//    per instr = legal), x as splatted VGPR pairs formed once per row.
//    R3->R4 flatness showed the compiler scalarizes v2f fma; asm removes doubt.
//  - gelu evaluated pairwise on {h, h+1} with v2f arithmetic (packable fp32
//    ops; rcp/exp2 remain scalar transcendentals).
//  - phase 2 verbatim from R6 (validated: absmax 0.0039, zero top-3 flips).

constexpr int Bn = 524288, Cn = 13, Tn = 24, Hn = 64, En = 8, Kn = 3;

typedef float v2f __attribute__((ext_vector_type(2)));

#define RCPF(x) __builtin_amdgcn_rcpf(x)
#define EXP2F(x) __builtin_amdgcn_exp2f(x)

// scalar gelu (phase 2): a * (0.5 + 0.5*erf(a/sqrt2)), A&S 7.1.26 erf
__device__ __forceinline__ float fast_gelu(float a) {
    const float p  = 0.3275911f;
    const float c1 = 0.254829592f, c2 = -0.284496736f, c3 = 1.421413741f,
                c4 = -1.453152027f, c5 = 1.061405429f;
    float az = fabsf(a) * 0.70710678118654752f;
    float t  = RCPF(fmaf(p, az, 1.0f));
    float poly = fmaf(fmaf(fmaf(fmaf(c5, t, c4), t, c3), t, c2), t, c1) * t;
    float ez = EXP2F(az * az * -1.4426950408889634f);
    float e  = fmaf(-poly, ez, 1.0f);
    float es = copysignf(e, a);
    return a * fmaf(es, 0.5f, 0.5f);
}

// paired gelu (phase 1): same formula elementwise on a 2-vector
__device__ __forceinline__ v2f fast_gelu2(v2f a) {
    v2f az = __builtin_elementwise_abs(a) * 0.70710678118654752f;
    v2f den = az * 0.3275911f + 1.0f;
    v2f t;
    t.x = RCPF(den.x);
    t.y = RCPF(den.y);
    v2f poly = ((((1.061405429f * t - 1.453152027f) * t + 1.421413741f) * t
                 - 0.284496736f) * t + 0.254829592f) * t;
    v2f z2 = (az * az) * -1.4426950408889634f;
    v2f ez;
    ez.x = EXP2F(z2.x);
    ez.y = EXP2F(z2.y);
    v2f e = 1.0f - poly * ez;
    v2f es = __builtin_elementwise_copysign(e, a);
    return a * (es * 0.5f + 0.5f);
}

// fp64 ln(x) for x in (1e-10, 64), rel err ~1e-13 (validated R4-R6)
__device__ __forceinline__ double fast_log(double x) {
    long long bits = __double_as_longlong(x);
    int e = (int)(bits >> 52) - 1023;
    double m = __longlong_as_double((bits & 0x000FFFFFFFFFFFFFLL) |
                                    0x3FF0000000000000LL);
    if (m > 1.4142135623730951) { m *= 0.5; e += 1; }
    double num = m - 1.0, den = m + 1.0;
    double r = (double)RCPF((float)den);
    r = r * (2.0 - den * r);
    r = r * (2.0 - den * r);
    double s = num * r, s2 = s * s;
    double q = fma(s2, 1.0 / 15.0, 1.0 / 13.0);
    q = fma(s2, q, 1.0 / 11.0);
    q = fma(s2, q, 1.0 / 9.0);
    q = fma(s2, q, 1.0 / 7.0);
    q = fma(s2, q, 1.0 / 5.0);
    q = fma(s2, q, 1.0 / 3.0);
    q = fma(s2, q, 1.0);
    return fma((double)e, 0.6931471805599453, (s + s) * q);
}

__global__ __launch_bounds__(256, 4) void router_kernel(
    const float* __restrict__ ctx, const float* __restrict__ u,
    const float* __restrict__ tw1, const float* __restrict__ tb1,
    const float* __restrict__ tw2, const float* __restrict__ tb2,
    const float* __restrict__ cw1, const float* __restrict__ cb1,
    const float* __restrict__ cw2, const float* __restrict__ cb2,
    float* __restrict__ out)
{
    __shared__ float tv[256 * Cn];   // 13312 B

    const int tid = threadIdx.x;
    const long b0 = (long)blockIdx.x * 256;
    const float tb2v = tb2[0];

    // ================= phase 1: fc1+gelu+fc2 over 3328 rows =================
    #pragma unroll 1
    for (int k = 0; k < Cn; ++k) {
        const long g = b0 * Cn + (long)k * 256 + tid;     // row = (b,c) pair
        const float4* xp = reinterpret_cast<const float4*>(ctx + g * Tn);
        v2f xs[Tn];                                       // splat pairs {x,x}
        #pragma unroll
        for (int i = 0; i < Tn / 4; ++i) {
            float4 v = xp[i];
            xs[4 * i + 0] = (v2f){ v.x, v.x };
            xs[4 * i + 1] = (v2f){ v.y, v.y };
            xs[4 * i + 2] = (v2f){ v.z, v.z };
            xs[4 * i + 3] = (v2f){ v.w, v.w };
        }

        v2f tacc2 = { 0.0f, 0.0f };
        #pragma unroll
        for (int hb = 0; hb < Hn; hb += 16) {
            v2f a2[8];
            #pragma unroll
            for (int j = 0; j < 8; ++j)
                a2[j] = *reinterpret_cast<const v2f*>(tb1 + hb + 2 * j);
            #pragma unroll
            for (int t = 0; t < Tn; ++t) {
                const unsigned long long* wp =
                    reinterpret_cast<const unsigned long long*>(tw1 + t * Hn + hb);
                #pragma unroll
                for (int j = 0; j < 8; ++j) {
                    // a2[j] = {x,x} * {w_h, w_h+1} + a2[j]  (packed fp32)
                    asm("v_pk_fma_f32 %0, %1, %2, %0"
                        : "+v"(a2[j])
                        : "v"(xs[t]), "s"(wp[j]));
                }
            }
            const unsigned long long* w2p =
                reinterpret_cast<const unsigned long long*>(tw2 + hb);
            #pragma unroll
            for (int j = 0; j < 8; ++j) {
                v2f g2 = fast_gelu2(a2[j]);
                asm("v_pk_fma_f32 %0, %1, %2, %0"
                    : "+v"(tacc2)
                    : "v"(g2), "s"(w2p[j]));
            }
        }
        tv[k * 256 + tid] = tacc2.x + tacc2.y + tb2v;
    }

    __syncthreads();

    // ================= phase 2: per-b c_mlp + gumbel + softmax + topk =======
    const long b = b0 + tid;

    float t13[Cn];
    #pragma unroll
    for (int c = 0; c < Cn; ++c) t13[c] = tv[tid * Cn + c];

    float logits[En];
    #pragma unroll
    for (int e = 0; e < En; ++e) logits[e] = cb2[e];

    #pragma unroll 1
    for (int h = 0; h < Hn; ++h) {
        float a = cb1[h];
        #pragma unroll
        for (int c = 0; c < Cn; ++c)
            a = fmaf(t13[c], cw1[c * Hn + h], a);
        float gg = fast_gelu(a);
        #pragma unroll
        for (int e = 0; e < En; ++e)
            logits[e] = fmaf(gg, cw2[h * En + e], logits[e]);
    }

    // gumbel (custom fp64 logs), y = logits + g
    const float4* up = reinterpret_cast<const float4*>(u + b * En);
    float4 u0 = up[0], u1 = up[1];
    float uv[En] = { u0.x, u0.y, u0.z, u0.w, u1.x, u1.y, u1.z, u1.w };

    double y[En];
    #pragma unroll
    for (int e = 0; e < En; ++e) {
        double w = -fast_log((double)uv[e]);
        y[e] = (double)logits[e] - fast_log(w + 1e-10);   // tau = 1
    }

    // softmax in fp32 (probs compared at bf16 tolerance)
    double m = y[0];
    #pragma unroll
    for (int e = 1; e < En; ++e) m = fmax(m, y[e]);
    float p[En], s = 0.0f;
    #pragma unroll
    for (int e = 0; e < En; ++e) {
        p[e] = EXP2F((float)(y[e] - m) * 1.4426950408889634f);
        s += p[e];
    }
    float inv = RCPF(s);

    // top-3 on y (fp64 ordering == probs ordering), bitmask
    unsigned sel = 0u;
    #pragma unroll
    for (int k = 0; k < Kn; ++k) {
        int best = 0;
        double bv = -1.0e300;
        #pragma unroll
        for (int e = 0; e < En; ++e) {
            bool ok = (((sel >> e) & 1u) == 0u) && (y[e] > bv);
            bv = ok ? y[e] : bv;
            best = ok ? e : best;
        }
        sel |= (1u << best);
    }

    // stores
    float4* om = reinterpret_cast<float4*>(out + b * En);
    om[0] = make_float4((sel >> 0) & 1u, (sel >> 1) & 1u,
                        (sel >> 2) & 1u, (sel >> 3) & 1u);
    om[1] = make_float4((sel >> 4) & 1u, (sel >> 5) & 1u,
                        (sel >> 6) & 1u, (sel >> 7) & 1u);
    float4* op = reinterpret_cast<float4*>(out + (long)Bn * En + b * En);
    op[0] = make_float4(p[0] * inv, p[1] * inv, p[2] * inv, p[3] * inv);
    op[1] = make_float4(p[4] * inv, p[5] * inv, p[6] * inv, p[7] * inv);
}

extern "C" void kernel_launch(void* const* d_in, const int* in_sizes, int n_in,
                              void* d_out, int out_size, void* d_ws, size_t ws_size,
                              hipStream_t stream) {
    const float* ctx = (const float*)d_in[0];
    const float* u   = (const float*)d_in[1];
    const float* tw1 = (const float*)d_in[2];
    const float* tb1 = (const float*)d_in[3];
    const float* tw2 = (const float*)d_in[4];
    const float* tb2 = (const float*)d_in[5];
    const float* cw1 = (const float*)d_in[6];
    const float* cb1 = (const float*)d_in[7];
    const float* cw2 = (const float*)d_in[8];
    const float* cb2 = (const float*)d_in[9];
    float* out = (float*)d_out;

    dim3 grid(Bn / 256), block(256);
    router_kernel<<<grid, block, 0, stream>>>(ctx, u, tw1, tb1, tw2, tb2,
                                              cw1, cb1, cw2, cb2, out);
}

// Round 8
// 419.173 us; speedup vs baseline: 1.6844x; 1.6844x over previous
//
#include <hip/hip_runtime.h>
#include <math.h>

// EnvAwareRouter: B=524288, C=13, T=24, H=64, E=8, K=3, tau=1, eps=1e-10
// Output: concat[ mask(B,E), probs(B,E) ] f32
//
// R8: fc1 on the matrix cores. fc1 = (B*C, 24)@(24, 64) GEMM done as
// mfma_f32_16x16x32_bf16 with bf16x3 splits (8 products, residual ~2^-27 ==
// same error class as the fp32 scalar fc1 that passed R2-R6). Weights live
// wave-stationary in 48 VGPRs as B-fragments (the thing R7's SGPR-asm path
// structurally couldn't do). K 24->32 padded by ZERO B-frags in lane-group 3
// (A-garbage x B-zero = 0, so A needs no masking).
//   - 1-wave (64-thread) blocks x 8192; block = 64 b = 832 rows.
//   - 26 super-iters: stage 32 rows to LDS as packed bf16x3 (48 B/row/split,
//     36-word stride -> <=2-way banks = free), ds_read_b128 fragments.
//   - epilogue: gelu x16/lane + fc2 partial + 4-step shfl_xor butterfly
//     over the 16-lane col group -> tv[832] in LDS.
//   - phase 2 (c_mlp/gumbel/softmax/topk) verbatim R6 numerics (validated).

constexpr int Bn = 524288, Cn = 13, Tn = 24, Hn = 64, En = 8, Kn = 3;

typedef __attribute__((ext_vector_type(8))) short bf16x8;
typedef __attribute__((ext_vector_type(4))) float f32x4;

#define RCPF(x) __builtin_amdgcn_rcpf(x)
#define EXP2F(x) __builtin_amdgcn_exp2f(x)

__device__ __forceinline__ unsigned short bf16_rne(float f) {
    unsigned u = __float_as_uint(f);
    unsigned r = u + 0x7FFFu + ((u >> 16) & 1u);
    return (unsigned short)(r >> 16);
}
__device__ __forceinline__ float bf16_f(unsigned short h) {
    return __uint_as_float(((unsigned)h) << 16);
}
__device__ __forceinline__ void split3(float x, unsigned short& h0,
                                       unsigned short& h1, unsigned short& h2) {
    h0 = bf16_rne(x);
    float r = x - bf16_f(h0);
    h1 = bf16_rne(r);
    h2 = bf16_rne(r - bf16_f(h1));
}

// gelu: a * (0.5 + 0.5*erf(a/sqrt2)), A&S 7.1.26 erf (validated R2-R7)
__device__ __forceinline__ float fast_gelu(float a) {
    const float p  = 0.3275911f;
    const float c1 = 0.254829592f, c2 = -0.284496736f, c3 = 1.421413741f,
                c4 = -1.453152027f, c5 = 1.061405429f;
    float az = fabsf(a) * 0.70710678118654752f;
    float t  = RCPF(fmaf(p, az, 1.0f));
    float poly = fmaf(fmaf(fmaf(fmaf(c5, t, c4), t, c3), t, c2), t, c1) * t;
    float ez = EXP2F(az * az * -1.4426950408889634f);
    float e  = fmaf(-poly, ez, 1.0f);
    float es = copysignf(e, a);
    return a * fmaf(es, 0.5f, 0.5f);
}

// fp64 ln(x), x in (1e-10, 64), rel err ~1e-13 (validated R4-R7)
__device__ __forceinline__ double fast_log(double x) {
    long long bits = __double_as_longlong(x);
    int e = (int)(bits >> 52) - 1023;
    double m = __longlong_as_double((bits & 0x000FFFFFFFFFFFFFLL) |
                                    0x3FF0000000000000LL);
    if (m > 1.4142135623730951) { m *= 0.5; e += 1; }
    double num = m - 1.0, den = m + 1.0;
    double r = (double)RCPF((float)den);
    r = r * (2.0 - den * r);
    r = r * (2.0 - den * r);
    double s = num * r, s2 = s * s;
    double q = fma(s2, 1.0 / 15.0, 1.0 / 13.0);
    q = fma(s2, q, 1.0 / 11.0);
    q = fma(s2, q, 1.0 / 9.0);
    q = fma(s2, q, 1.0 / 7.0);
    q = fma(s2, q, 1.0 / 5.0);
    q = fma(s2, q, 1.0 / 3.0);
    q = fma(s2, q, 1.0);
    return fma((double)e, 0.6931471805599453, (s + s) * q);
}

__global__ __launch_bounds__(64) void router_kernel(
    const float* __restrict__ ctx, const float* __restrict__ u,
    const float* __restrict__ tw1, const float* __restrict__ tb1,
    const float* __restrict__ tw2, const float* __restrict__ tb2,
    const float* __restrict__ cw1, const float* __restrict__ cb1,
    const float* __restrict__ cw2, const float* __restrict__ cb2,
    float* __restrict__ out)
{
    __shared__ unsigned stageU[32 * 3 * 12];  // 32 row-slots x 3 splits x 12 u32
    __shared__ float tv[64 * Cn];             // 832 t values

    const int l = threadIdx.x;                // 0..63
    const long B0 = (long)blockIdx.x * 64;
    const int col = l & 15;                   // MFMA col / A row within tile
    const int kgrp = l >> 4;                  // k-group 0..3 (8 k's each)

    // ---- wave-stationary B-fragments: tw1 in bf16x3 (+ fc2/bias regs) ----
    bf16x8 Bf[3][4];                          // [split][col-tile]
    float w2v[4], biasv[4];
    #pragma unroll
    for (int ct = 0; ct < 4; ++ct) {
        const int h = ct * 16 + col;
        w2v[ct] = tw2[h];
        biasv[ct] = tb1[h];
        #pragma unroll
        for (int j = 0; j < 8; ++j) {
            const int k = kgrp * 8 + j;
            float w = (k < Tn) ? tw1[k * Hn + h] : 0.0f;  // K-pad: zero B
            unsigned short w0, w1, w2s;
            split3(w, w0, w1, w2s);
            Bf[0][ct][j] = (short)w0;
            Bf[1][ct][j] = (short)w1;
            Bf[2][ct][j] = (short)w2s;
        }
    }
    const float tb2v = tb2[0];

    // ================= phase 1: fc1 via MFMA + gelu + fc2 ==================
    const long rowBase = B0 * Cn;             // 832 rows: [rowBase, rowBase+832)
    #pragma unroll 1
    for (int si = 0; si < 26; ++si) {
        // ---- stage 32 rows as packed bf16x3 (2 lanes/row, 12 el each) ----
        {
            const int slot = l >> 1, half = l & 1;
            const float4* sp = reinterpret_cast<const float4*>(
                ctx + (rowBase + (long)si * 32 + slot) * Tn + half * 12);
            float4 v0 = sp[0], v1 = sp[1], v2 = sp[2];
            float xv[12] = { v0.x, v0.y, v0.z, v0.w, v1.x, v1.y, v1.z, v1.w,
                             v2.x, v2.y, v2.z, v2.w };
            unsigned pk0[6], pk1[6], pk2[6];
            #pragma unroll
            for (int j = 0; j < 6; ++j) {
                unsigned short a0, a1, a2, b0, b1, b2;
                split3(xv[2 * j + 0], a0, a1, a2);
                split3(xv[2 * j + 1], b0, b1, b2);
                pk0[j] = (unsigned)a0 | ((unsigned)b0 << 16);
                pk1[j] = (unsigned)a1 | ((unsigned)b1 << 16);
                pk2[j] = (unsigned)a2 | ((unsigned)b2 << 16);
            }
            unsigned* d0 = &stageU[(slot * 3 + 0) * 12 + half * 6];
            unsigned* d1 = &stageU[(slot * 3 + 1) * 12 + half * 6];
            unsigned* d2 = &stageU[(slot * 3 + 2) * 12 + half * 6];
            *reinterpret_cast<uint2*>(d0 + 0) = make_uint2(pk0[0], pk0[1]);
            *reinterpret_cast<uint2*>(d0 + 2) = make_uint2(pk0[2], pk0[3]);
            *reinterpret_cast<uint2*>(d0 + 4) = make_uint2(pk0[4], pk0[5]);
            *reinterpret_cast<uint2*>(d1 + 0) = make_uint2(pk1[0], pk1[1]);
            *reinterpret_cast<uint2*>(d1 + 2) = make_uint2(pk1[2], pk1[3]);
            *reinterpret_cast<uint2*>(d1 + 4) = make_uint2(pk1[4], pk1[5]);
            *reinterpret_cast<uint2*>(d2 + 0) = make_uint2(pk2[0], pk2[1]);
            *reinterpret_cast<uint2*>(d2 + 2) = make_uint2(pk2[2], pk2[3]);
            *reinterpret_cast<uint2*>(d2 + 4) = make_uint2(pk2[4], pk2[5]);
        }
        __syncthreads();   // 1-wave block: compiles to waitcnt ordering

        // ---- two 16-row M-tiles ----
        #pragma unroll
        for (int tt = 0; tt < 2; ++tt) {
            const int slotrow = tt * 16 + col;
            const int koff = (kgrp < 3 ? kgrp : 2) * 4;  // kgrp3 reads junk; B=0
            bf16x8 Af0 = *reinterpret_cast<const bf16x8*>(
                &stageU[(slotrow * 3 + 0) * 12 + koff]);
            bf16x8 Af1 = *reinterpret_cast<const bf16x8*>(
                &stageU[(slotrow * 3 + 1) * 12 + koff]);
            bf16x8 Af2 = *reinterpret_cast<const bf16x8*>(
                &stageU[(slotrow * 3 + 2) * 12 + koff]);

            f32x4 acc[4];
            #pragma unroll
            for (int ct = 0; ct < 4; ++ct)
                acc[ct] = (f32x4){ biasv[ct], biasv[ct], biasv[ct], biasv[ct] };

            #pragma unroll
            for (int ct = 0; ct < 4; ++ct) {
                acc[ct] = __builtin_amdgcn_mfma_f32_16x16x32_bf16(Af0, Bf[0][ct], acc[ct], 0, 0, 0);
                acc[ct] = __builtin_amdgcn_mfma_f32_16x16x32_bf16(Af0, Bf[1][ct], acc[ct], 0, 0, 0);
                acc[ct] = __builtin_amdgcn_mfma_f32_16x16x32_bf16(Af1, Bf[0][ct], acc[ct], 0, 0, 0);
                acc[ct] = __builtin_amdgcn_mfma_f32_16x16x32_bf16(Af1, Bf[1][ct], acc[ct], 0, 0, 0);
                acc[ct] = __builtin_amdgcn_mfma_f32_16x16x32_bf16(Af0, Bf[2][ct], acc[ct], 0, 0, 0);
                acc[ct] = __builtin_amdgcn_mfma_f32_16x16x32_bf16(Af2, Bf[0][ct], acc[ct], 0, 0, 0);
                acc[ct] = __builtin_amdgcn_mfma_f32_16x16x32_bf16(Af1, Bf[2][ct], acc[ct], 0, 0, 0);
                acc[ct] = __builtin_amdgcn_mfma_f32_16x16x32_bf16(Af2, Bf[1][ct], acc[ct], 0, 0, 0);
            }

            // gelu + fc2 partials (C/D layout: col=l&15, row=kgrp*4+reg)
            float p0 = 0.0f, p1 = 0.0f, p2 = 0.0f, p3 = 0.0f;
            #pragma unroll
            for (int ct = 0; ct < 4; ++ct) {
                p0 = fmaf(fast_gelu(acc[ct][0]), w2v[ct], p0);
                p1 = fmaf(fast_gelu(acc[ct][1]), w2v[ct], p1);
                p2 = fmaf(fast_gelu(acc[ct][2]), w2v[ct], p2);
                p3 = fmaf(fast_gelu(acc[ct][3]), w2v[ct], p3);
            }
            #pragma unroll
            for (int m = 1; m < 16; m <<= 1) {
                p0 += __shfl_xor(p0, m);
                p1 += __shfl_xor(p1, m);
                p2 += __shfl_xor(p2, m);
                p3 += __shfl_xor(p3, m);
            }
            if (col < 4) {   // 16 writer lanes -> 16 rows of this tile
                float val = (col & 1) ? ((col & 2) ? p3 : p1)
                                      : ((col & 2) ? p2 : p0);
                tv[si * 32 + tt * 16 + kgrp * 4 + col] = val + tb2v;
            }
        }
        __syncthreads();   // order tile reads before next iter's stage writes
    }

    // ================= phase 2: per-b c_mlp + gumbel + softmax + topk =======
    const long b = B0 + l;

    float t13[Cn];
    #pragma unroll
    for (int c = 0; c < Cn; ++c) t13[c] = tv[l * Cn + c];

    float logits[En];
    #pragma unroll
    for (int e = 0; e < En; ++e) logits[e] = cb2[e];

    #pragma unroll 1
    for (int h = 0; h < Hn; ++h) {
        float a = cb1[h];
        #pragma unroll
        for (int c = 0; c < Cn; ++c)
            a = fmaf(t13[c], cw1[c * Hn + h], a);
        float gg = fast_gelu(a);
        #pragma unroll
        for (int e = 0; e < En; ++e)
            logits[e] = fmaf(gg, cw2[h * En + e], logits[e]);
    }

    // gumbel (custom fp64 logs), y = logits + g
    const float4* up = reinterpret_cast<const float4*>(u + b * En);
    float4 u0 = up[0], u1 = up[1];
    float uv[En] = { u0.x, u0.y, u0.z, u0.w, u1.x, u1.y, u1.z, u1.w };

    double y[En];
    #pragma unroll
    for (int e = 0; e < En; ++e) {
        double w = -fast_log((double)uv[e]);
        y[e] = (double)logits[e] - fast_log(w + 1e-10);   // tau = 1
    }

    // softmax in fp32 (probs compared at bf16 tolerance)
    double m = y[0];
    #pragma unroll
    for (int e = 1; e < En; ++e) m = fmax(m, y[e]);
    float p[En], s = 0.0f;
    #pragma unroll
    for (int e = 0; e < En; ++e) {
        p[e] = EXP2F((float)(y[e] - m) * 1.4426950408889634f);
        s += p[e];
    }
    float inv = RCPF(s);

    // top-3 on y (fp64 ordering == probs ordering), bitmask
    unsigned sel = 0u;
    #pragma unroll
    for (int k = 0; k < Kn; ++k) {
        int best = 0;
        double bv = -1.0e300;
        #pragma unroll
        for (int e = 0; e < En; ++e) {
            bool ok = (((sel >> e) & 1u) == 0u) && (y[e] > bv);
            bv = ok ? y[e] : bv;
            best = ok ? e : best;
        }
        sel |= (1u << best);
    }

    // stores
    float4* om = reinterpret_cast<float4*>(out + b * En);
    om[0] = make_float4((sel >> 0) & 1u, (sel >> 1) & 1u,
                        (sel >> 2) & 1u, (sel >> 3) & 1u);
    om[1] = make_float4((sel >> 4) & 1u, (sel >> 5) & 1u,
                        (sel >> 6) & 1u, (sel >> 7) & 1u);
    float4* op = reinterpret_cast<float4*>(out + (long)Bn * En + b * En);
    op[0] = make_float4(p[0] * inv, p[1] * inv, p[2] * inv, p[3] * inv);
    op[1] = make_float4(p[4] * inv, p[5] * inv, p[6] * inv, p[7] * inv);
}

extern "C" void kernel_launch(void* const* d_in, const int* in_sizes, int n_in,
                              void* d_out, int out_size, void* d_ws, size_t ws_size,
                              hipStream_t stream) {
    const float* ctx = (const float*)d_in[0];
    const float* u   = (const float*)d_in[1];
    const float* tw1 = (const float*)d_in[2];
    const float* tb1 = (const float*)d_in[3];
    const float* tw2 = (const float*)d_in[4];
    const float* tb2 = (const float*)d_in[5];
    const float* cw1 = (const float*)d_in[6];
    const float* cb1 = (const float*)d_in[7];
    const float* cw2 = (const float*)d_in[8];
    const float* cb2 = (const float*)d_in[9];
    float* out = (float*)d_out;

    dim3 grid(Bn / 64), block(64);
    router_kernel<<<grid, block, 0, stream>>>(ctx, u, tw1, tb1, tw2, tb2,
                                              cw1, cb1, cw2, cb2, out);
}

// Round 9
// 396.195 us; speedup vs baseline: 1.7821x; 1.0580x over previous
//
#include <hip/hip_runtime.h>
#include <math.h>

// EnvAwareRouter: B=524288, C=13, T=24, H=64, E=8, K=3, tau=1, eps=1e-10
// Output: concat[ mask(B,E), probs(B,E) ] f32
//
// R9 = R8 MFMA structure, occupancy + staging-cost fixes.
//  - 256-thread blocks (4 waves, per-wave-private stage/tv LDS regions):
//    R8's 1-wave WGs hit the ~12-16 workgroup/CU slot cap (occ 38%), starving
//    the trans pipe (2 trans/gelu x ~900 gelus/lane) of overlap waves.
//  - stage raw fp32 rows (3x ds_write_b128, no math); bf16x3 split AFTER the
//    fragment read via v_cvt_pk_bf16_f32 (11 inst/pair vs 34 bit-twiddled).
//    Each (row,k) element is consumed by exactly one lane -> split once.
//  - fc2 16-lane reduction via DPP (quad_perm/row_half_mirror/row_mirror
//    butterfly: xor1,xor2,xor7,xor15 -> valid sum-reduction net), no bpermute.
//  - MFMA: mfma_f32_16x16x32_bf16, 8 split-products (residual ~2^-27),
//    K 24->32 zero-padded via zero B-frags for kgrp3 (validated R8).
//  - phase 2 (c_mlp/gumbel/softmax/topk) verbatim R6-R8 (validated).

constexpr int Bn = 524288, Cn = 13, Tn = 24, Hn = 64, En = 8, Kn = 3;
constexpr int WAVES = 4;

typedef __attribute__((ext_vector_type(8))) short bf16x8;
typedef __attribute__((ext_vector_type(4))) float f32x4;

#define RCPF(x) __builtin_amdgcn_rcpf(x)
#define EXP2F(x) __builtin_amdgcn_exp2f(x)

__device__ __forceinline__ unsigned short bf16_rne(float f) {
    unsigned u = __float_as_uint(f);
    unsigned r = u + 0x7FFFu + ((u >> 16) & 1u);
    return (unsigned short)(r >> 16);
}
__device__ __forceinline__ float bf16_f(unsigned short h) {
    return __uint_as_float(((unsigned)h) << 16);
}
__device__ __forceinline__ void split3(float x, unsigned short& h0,
                                       unsigned short& h1, unsigned short& h2) {
    h0 = bf16_rne(x);
    float r = x - bf16_f(h0);
    h1 = bf16_rne(r);
    h2 = bf16_rne(r - bf16_f(h1));
}

// split a pair of fp32 into 3 packed-bf16 words via HW cvt (RNE, same
// semantics as split3): p0..p2 hold {lo=a_s, hi=b_s} for splits s=0..2
__device__ __forceinline__ void split_pair(float a, float b, unsigned& p0,
                                           unsigned& p1, unsigned& p2) {
    asm("v_cvt_pk_bf16_f32 %0, %1, %2" : "=v"(p0) : "v"(a), "v"(b));
    float ra = a - __uint_as_float(p0 << 16);
    float rb = b - __uint_as_float(p0 & 0xFFFF0000u);
    asm("v_cvt_pk_bf16_f32 %0, %1, %2" : "=v"(p1) : "v"(ra), "v"(rb));
    float ra2 = ra - __uint_as_float(p1 << 16);
    float rb2 = rb - __uint_as_float(p1 & 0xFFFF0000u);
    asm("v_cvt_pk_bf16_f32 %0, %1, %2" : "=v"(p2) : "v"(ra2), "v"(rb2));
}

// gelu: a * (0.5 + 0.5*erf(a/sqrt2)), A&S 7.1.26 erf (validated R2-R8)
__device__ __forceinline__ float fast_gelu(float a) {
    const float p  = 0.3275911f;
    const float c1 = 0.254829592f, c2 = -0.284496736f, c3 = 1.421413741f,
                c4 = -1.453152027f, c5 = 1.061405429f;
    float az = fabsf(a) * 0.70710678118654752f;
    float t  = RCPF(fmaf(p, az, 1.0f));
    float poly = fmaf(fmaf(fmaf(fmaf(c5, t, c4), t, c3), t, c2), t, c1) * t;
    float ez = EXP2F(az * az * -1.4426950408889634f);
    float e  = fmaf(-poly, ez, 1.0f);
    float es = copysignf(e, a);
    return a * fmaf(es, 0.5f, 0.5f);
}

// fp64 ln(x), x in (1e-10, 64), rel err ~1e-13 (validated R4-R8)
__device__ __forceinline__ double fast_log(double x) {
    long long bits = __double_as_longlong(x);
    int e = (int)(bits >> 52) - 1023;
    double m = __longlong_as_double((bits & 0x000FFFFFFFFFFFFFLL) |
                                    0x3FF0000000000000LL);
    if (m > 1.4142135623730951) { m *= 0.5; e += 1; }
    double num = m - 1.0, den = m + 1.0;
    double r = (double)RCPF((float)den);
    r = r * (2.0 - den * r);
    r = r * (2.0 - den * r);
    double s = num * r, s2 = s * s;
    double q = fma(s2, 1.0 / 15.0, 1.0 / 13.0);
    q = fma(s2, q, 1.0 / 11.0);
    q = fma(s2, q, 1.0 / 9.0);
    q = fma(s2, q, 1.0 / 7.0);
    q = fma(s2, q, 1.0 / 5.0);
    q = fma(s2, q, 1.0 / 3.0);
    q = fma(s2, q, 1.0);
    return fma((double)e, 0.6931471805599453, (s + s) * q);
}

// 16-lane-group sum via DPP butterfly: xor1, xor2, xor7, xor15
// (quad_perm[1,0,3,2]=0xB1, quad_perm[2,3,0,1]=0x4E,
//  row_half_mirror=0x141, row_mirror=0x140) — valid reduction net.
__device__ __forceinline__ float dpp_reduce16(float p) {
    p += __int_as_float(__builtin_amdgcn_update_dpp(
        0, __float_as_int(p), 0xB1, 0xF, 0xF, true));
    p += __int_as_float(__builtin_amdgcn_update_dpp(
        0, __float_as_int(p), 0x4E, 0xF, 0xF, true));
    p += __int_as_float(__builtin_amdgcn_update_dpp(
        0, __float_as_int(p), 0x141, 0xF, 0xF, true));
    p += __int_as_float(__builtin_amdgcn_update_dpp(
        0, __float_as_int(p), 0x140, 0xF, 0xF, true));
    return p;
}

__global__ __launch_bounds__(256) void router_kernel(
    const float* __restrict__ ctx, const float* __restrict__ u,
    const float* __restrict__ tw1, const float* __restrict__ tb1,
    const float* __restrict__ tw2, const float* __restrict__ tb2,
    const float* __restrict__ cw1, const float* __restrict__ cb1,
    const float* __restrict__ cw2, const float* __restrict__ cb2,
    float* __restrict__ out)
{
    __shared__ float stage[WAVES][32][24];     // raw fp32 rows, 12.3 KB
    __shared__ float tv[WAVES][64 * Cn];       // t values, 13.3 KB

    const int tid = threadIdx.x;
    const int wid = tid >> 6;
    const int l = tid & 63;
    const long bw = (long)blockIdx.x * 256 + wid * 64;   // wave owns 64 b
    const int col = l & 15;                    // MFMA col / A row in tile
    const int kgrp = l >> 4;                   // k-group 0..3
    const int koff = (kgrp < 3 ? kgrp : 2) * 8;  // kgrp3 dups kgrp2 (B=0)

    // ---- wave-stationary B-fragments: tw1 bf16x3, + fc2/bias regs ----
    bf16x8 Bf[3][4];
    float w2v[4], biasv[4];
    #pragma unroll
    for (int ct = 0; ct < 4; ++ct) {
        const int h = ct * 16 + col;
        w2v[ct] = tw2[h];
        biasv[ct] = tb1[h];
        #pragma unroll
        for (int j = 0; j < 8; ++j) {
            const int k = kgrp * 8 + j;
            float w = (k < Tn) ? tw1[k * Hn + h] : 0.0f;   // K-pad: zero B
            unsigned short w0, w1, w2s;
            split3(w, w0, w1, w2s);
            Bf[0][ct][j] = (short)w0;
            Bf[1][ct][j] = (short)w1;
            Bf[2][ct][j] = (short)w2s;
        }
    }
    const float tb2v = tb2[0];

    // ================= phase 1: fc1 via MFMA + gelu + fc2 ==================
    const long rowBase = bw * Cn;              // 832 rows per wave
    const int slot = l >> 1, half = l & 1;
    #pragma unroll 1
    for (int si = 0; si < 26; ++si) {
        // ---- stage 32 raw fp32 rows (2 lanes/row, 12 floats each) ----
        {
            const float4* sp = reinterpret_cast<const float4*>(
                ctx + (rowBase + (long)si * 32 + slot) * Tn + half * 12);
            float4 v0 = sp[0], v1 = sp[1], v2 = sp[2];
            float4* d = reinterpret_cast<float4*>(&stage[wid][slot][half * 12]);
            d[0] = v0; d[1] = v1; d[2] = v2;
        }
        __syncthreads();

        // ---- two 16-row M-tiles ----
        #pragma unroll
        for (int tt = 0; tt < 2; ++tt) {
            const float* xr = &stage[wid][tt * 16 + col][koff];
            float4 xa = *reinterpret_cast<const float4*>(xr);
            float4 xb = *reinterpret_cast<const float4*>(xr + 4);

            union { unsigned w[4]; bf16x8 v; } F0, F1, F2;
            split_pair(xa.x, xa.y, F0.w[0], F1.w[0], F2.w[0]);
            split_pair(xa.z, xa.w, F0.w[1], F1.w[1], F2.w[1]);
            split_pair(xb.x, xb.y, F0.w[2], F1.w[2], F2.w[2]);
            split_pair(xb.z, xb.w, F0.w[3], F1.w[3], F2.w[3]);
            bf16x8 Af0 = F0.v, Af1 = F1.v, Af2 = F2.v;

            f32x4 acc[4];
            #pragma unroll
            for (int ct = 0; ct < 4; ++ct)
                acc[ct] = (f32x4){ biasv[ct], biasv[ct], biasv[ct], biasv[ct] };

            #pragma unroll
            for (int ct = 0; ct < 4; ++ct) {
                acc[ct] = __builtin_amdgcn_mfma_f32_16x16x32_bf16(Af0, Bf[0][ct], acc[ct], 0, 0, 0);
                acc[ct] = __builtin_amdgcn_mfma_f32_16x16x32_bf16(Af0, Bf[1][ct], acc[ct], 0, 0, 0);
                acc[ct] = __builtin_amdgcn_mfma_f32_16x16x32_bf16(Af1, Bf[0][ct], acc[ct], 0, 0, 0);
                acc[ct] = __builtin_amdgcn_mfma_f32_16x16x32_bf16(Af1, Bf[1][ct], acc[ct], 0, 0, 0);
                acc[ct] = __builtin_amdgcn_mfma_f32_16x16x32_bf16(Af0, Bf[2][ct], acc[ct], 0, 0, 0);
                acc[ct] = __builtin_amdgcn_mfma_f32_16x16x32_bf16(Af2, Bf[0][ct], acc[ct], 0, 0, 0);
                acc[ct] = __builtin_amdgcn_mfma_f32_16x16x32_bf16(Af1, Bf[2][ct], acc[ct], 0, 0, 0);
                acc[ct] = __builtin_amdgcn_mfma_f32_16x16x32_bf16(Af2, Bf[1][ct], acc[ct], 0, 0, 0);
            }

            // gelu + fc2 partials (C/D: col=l&15, row=kgrp*4+reg)
            float p0 = 0.0f, p1 = 0.0f, p2 = 0.0f, p3 = 0.0f;
            #pragma unroll
            for (int ct = 0; ct < 4; ++ct) {
                p0 = fmaf(fast_gelu(acc[ct][0]), w2v[ct], p0);
                p1 = fmaf(fast_gelu(acc[ct][1]), w2v[ct], p1);
                p2 = fmaf(fast_gelu(acc[ct][2]), w2v[ct], p2);
                p3 = fmaf(fast_gelu(acc[ct][3]), w2v[ct], p3);
            }
            p0 = dpp_reduce16(p0);
            p1 = dpp_reduce16(p1);
            p2 = dpp_reduce16(p2);
            p3 = dpp_reduce16(p3);
            if (col < 4) {   // 16 writer lanes -> 16 rows of this tile
                float val = (col & 1) ? ((col & 2) ? p3 : p1)
                                      : ((col & 2) ? p2 : p0);
                tv[wid][si * 32 + tt * 16 + kgrp * 4 + col] = val + tb2v;
            }
        }
        __syncthreads();   // protect stage from next iter's overwrite
    }

    // ================= phase 2: per-b c_mlp + gumbel + softmax + topk =======
    const long b = bw + l;

    float t13[Cn];
    #pragma unroll
    for (int c = 0; c < Cn; ++c) t13[c] = tv[wid][l * Cn + c];

    float logits[En];
    #pragma unroll
    for (int e = 0; e < En; ++e) logits[e] = cb2[e];

    #pragma unroll 1
    for (int h = 0; h < Hn; ++h) {
        float a = cb1[h];
        #pragma unroll
        for (int c = 0; c < Cn; ++c)
            a = fmaf(t13[c], cw1[c * Hn + h], a);
        float gg = fast_gelu(a);
        #pragma unroll
        for (int e = 0; e < En; ++e)
            logits[e] = fmaf(gg, cw2[h * En + e], logits[e]);
    }

    // gumbel (custom fp64 logs), y = logits + g
    const float4* up = reinterpret_cast<const float4*>(u + b * En);
    float4 u0 = up[0], u1 = up[1];
    float uv[En] = { u0.x, u0.y, u0.z, u0.w, u1.x, u1.y, u1.z, u1.w };

    double y[En];
    #pragma unroll
    for (int e = 0; e < En; ++e) {
        double w = -fast_log((double)uv[e]);
        y[e] = (double)logits[e] - fast_log(w + 1e-10);   // tau = 1
    }

    // softmax in fp32 (probs compared at bf16 tolerance)
    double m = y[0];
    #pragma unroll
    for (int e = 1; e < En; ++e) m = fmax(m, y[e]);
    float p[En], s = 0.0f;
    #pragma unroll
    for (int e = 0; e < En; ++e) {
        p[e] = EXP2F((float)(y[e] - m) * 1.4426950408889634f);
        s += p[e];
    }
    float inv = RCPF(s);

    // top-3 on y (fp64 ordering == probs ordering), bitmask
    unsigned sel = 0u;
    #pragma unroll
    for (int k = 0; k < Kn; ++k) {
        int best = 0;
        double bv = -1.0e300;
        #pragma unroll
        for (int e = 0; e < En; ++e) {
            bool ok = (((sel >> e) & 1u) == 0u) && (y[e] > bv);
            bv = ok ? y[e] : bv;
            best = ok ? e : best;
        }
        sel |= (1u << best);
    }

    // stores
    float4* om = reinterpret_cast<float4*>(out + b * En);
    om[0] = make_float4((sel >> 0) & 1u, (sel >> 1) & 1u,
                        (sel >> 2) & 1u, (sel >> 3) & 1u);
    om[1] = make_float4((sel >> 4) & 1u, (sel >> 5) & 1u,
                        (sel >> 6) & 1u, (sel >> 7) & 1u);
    float4* op = reinterpret_cast<float4*>(out + (long)Bn * En + b * En);
    op[0] = make_float4(p[0] * inv, p[1] * inv, p[2] * inv, p[3] * inv);
    op[1] = make_float4(p[4] * inv, p[5] * inv, p[6] * inv, p[7] * inv);
}

extern "C" void kernel_launch(void* const* d_in, const int* in_sizes, int n_in,
                              void* d_out, int out_size, void* d_ws, size_t ws_size,
                              hipStream_t stream) {
    const float* ctx = (const float*)d_in[0];
    const float* u   = (const float*)d_in[1];
    const float* tw1 = (const float*)d_in[2];
    const float* tb1 = (const float*)d_in[3];
    const float* tw2 = (const float*)d_in[4];
    const float* tb2 = (const float*)d_in[5];
    const float* cw1 = (const float*)d_in[6];
    const float* cb1 = (const float*)d_in[7];
    const float* cw2 = (const float*)d_in[8];
    const float* cb2 = (const float*)d_in[9];
    float* out = (float*)d_out;

    dim3 grid(Bn / 256), block(256);
    router_kernel<<<grid, block, 0, stream>>>(ctx, u, tw1, tb1, tw2, tb2,
                                              cw1, cb1, cw2, cb2, out);
}

// Round 10
// 365.932 us; speedup vs baseline: 1.9295x; 1.0827x over previous
//
#include <hip/hip_runtime.h>
#include <math.h>

// EnvAwareRouter: B=524288, C=13, T=24, H=64, E=8, K=3, tau=1, eps=1e-10
// Output: concat[ mask(B,E), probs(B,E) ] f32
//
// R10 = R9 minus the entire staging pipeline (latency-bound diagnosis).
//  - A-fragments loaded DIRECTLY from global with per-lane addresses: lane
//    (col,kgrp) of tile tt reads ctx[(row)*24 + koff .. +8) as two float4s.
//    No stage LDS, no ds_write/ds_read in the hot loop, NO per-iteration
//    barriers -> waves independent; compiler free to pipeline si-loop loads
//    under prior MFMA/gelu. (R9 ran 3x above the ~131us issue floor ->
//    latency-bound; barriers+LDS round-trip were the exposed chains.)
//  - 6 split-products (drop (1,2),(2,1) ~2^-35): residual ~3e-8, within the
//    validated fp32-class envelope.
//  - single __syncthreads before phase 2 (cross-lane tv handoff).
//  - gelu/log/softmax/topk numerics verbatim R6-R9 (validated, absmax .0039).

constexpr int Bn = 524288, Cn = 13, Tn = 24, Hn = 64, En = 8, Kn = 3;
constexpr int WAVES = 4;

typedef __attribute__((ext_vector_type(8))) short bf16x8;
typedef __attribute__((ext_vector_type(4))) float f32x4;

#define RCPF(x) __builtin_amdgcn_rcpf(x)
#define EXP2F(x) __builtin_amdgcn_exp2f(x)

__device__ __forceinline__ unsigned short bf16_rne(float f) {
    unsigned u = __float_as_uint(f);
    unsigned r = u + 0x7FFFu + ((u >> 16) & 1u);
    return (unsigned short)(r >> 16);
}
__device__ __forceinline__ float bf16_f(unsigned short h) {
    return __uint_as_float(((unsigned)h) << 16);
}
__device__ __forceinline__ void split3(float x, unsigned short& h0,
                                       unsigned short& h1, unsigned short& h2) {
    h0 = bf16_rne(x);
    float r = x - bf16_f(h0);
    h1 = bf16_rne(r);
    h2 = bf16_rne(r - bf16_f(h1));
}

// split a pair of fp32 into 3 packed-bf16 words via HW cvt (RNE)
__device__ __forceinline__ void split_pair(float a, float b, unsigned& p0,
                                           unsigned& p1, unsigned& p2) {
    asm("v_cvt_pk_bf16_f32 %0, %1, %2" : "=v"(p0) : "v"(a), "v"(b));
    float ra = a - __uint_as_float(p0 << 16);
    float rb = b - __uint_as_float(p0 & 0xFFFF0000u);
    asm("v_cvt_pk_bf16_f32 %0, %1, %2" : "=v"(p1) : "v"(ra), "v"(rb));
    float ra2 = ra - __uint_as_float(p1 << 16);
    float rb2 = rb - __uint_as_float(p1 & 0xFFFF0000u);
    asm("v_cvt_pk_bf16_f32 %0, %1, %2" : "=v"(p2) : "v"(ra2), "v"(rb2));
}

// gelu: a * (0.5 + 0.5*erf(a/sqrt2)), A&S 7.1.26 erf (validated R2-R9)
__device__ __forceinline__ float fast_gelu(float a) {
    const float p  = 0.3275911f;
    const float c1 = 0.254829592f, c2 = -0.284496736f, c3 = 1.421413741f,
                c4 = -1.453152027f, c5 = 1.061405429f;
    float az = fabsf(a) * 0.70710678118654752f;
    float t  = RCPF(fmaf(p, az, 1.0f));
    float poly = fmaf(fmaf(fmaf(fmaf(c5, t, c4), t, c3), t, c2), t, c1) * t;
    float ez = EXP2F(az * az * -1.4426950408889634f);
    float e  = fmaf(-poly, ez, 1.0f);
    float es = copysignf(e, a);
    return a * fmaf(es, 0.5f, 0.5f);
}

// fp64 ln(x), x in (1e-10, 64), rel err ~1e-13 (validated R4-R9)
__device__ __forceinline__ double fast_log(double x) {
    long long bits = __double_as_longlong(x);
    int e = (int)(bits >> 52) - 1023;
    double m = __longlong_as_double((bits & 0x000FFFFFFFFFFFFFLL) |
                                    0x3FF0000000000000LL);
    if (m > 1.4142135623730951) { m *= 0.5; e += 1; }
    double num = m - 1.0, den = m + 1.0;
    double r = (double)RCPF((float)den);
    r = r * (2.0 - den * r);
    r = r * (2.0 - den * r);
    double s = num * r, s2 = s * s;
    double q = fma(s2, 1.0 / 15.0, 1.0 / 13.0);
    q = fma(s2, q, 1.0 / 11.0);
    q = fma(s2, q, 1.0 / 9.0);
    q = fma(s2, q, 1.0 / 7.0);
    q = fma(s2, q, 1.0 / 5.0);
    q = fma(s2, q, 1.0 / 3.0);
    q = fma(s2, q, 1.0);
    return fma((double)e, 0.6931471805599453, (s + s) * q);
}

// 16-lane-group sum via DPP butterfly (validated R9)
__device__ __forceinline__ float dpp_reduce16(float p) {
    p += __int_as_float(__builtin_amdgcn_update_dpp(
        0, __float_as_int(p), 0xB1, 0xF, 0xF, true));
    p += __int_as_float(__builtin_amdgcn_update_dpp(
        0, __float_as_int(p), 0x4E, 0xF, 0xF, true));
    p += __int_as_float(__builtin_amdgcn_update_dpp(
        0, __float_as_int(p), 0x141, 0xF, 0xF, true));
    p += __int_as_float(__builtin_amdgcn_update_dpp(
        0, __float_as_int(p), 0x140, 0xF, 0xF, true));
    return p;
}

__global__ __launch_bounds__(256, 4) void router_kernel(
    const float* __restrict__ ctx, const float* __restrict__ u,
    const float* __restrict__ tw1, const float* __restrict__ tb1,
    const float* __restrict__ tw2, const float* __restrict__ tb2,
    const float* __restrict__ cw1, const float* __restrict__ cb1,
    const float* __restrict__ cw2, const float* __restrict__ cb2,
    float* __restrict__ out)
{
    __shared__ float tv[WAVES][64 * Cn];       // per-wave t values, 13.3 KB

    const int tid = threadIdx.x;
    const int wid = tid >> 6;
    const int l = tid & 63;
    const long bw = (long)blockIdx.x * 256 + wid * 64;   // wave owns 64 b
    const int col = l & 15;                    // MFMA col / A row in tile
    const int kgrp = l >> 4;                   // k-group 0..3
    const int koff = (kgrp < 3 ? kgrp : 2) * 8;  // kgrp3 dups kgrp2 (B=0)

    // ---- wave-stationary B-fragments: tw1 bf16x3, + fc2/bias regs ----
    bf16x8 Bf[3][4];
    float w2v[4], biasv[4];
    #pragma unroll
    for (int ct = 0; ct < 4; ++ct) {
        const int h = ct * 16 + col;
        w2v[ct] = tw2[h];
        biasv[ct] = tb1[h];
        #pragma unroll
        for (int j = 0; j < 8; ++j) {
            const int k = kgrp * 8 + j;
            float w = (k < Tn) ? tw1[k * Hn + h] : 0.0f;   // K-pad: zero B
            unsigned short w0, w1, w2s;
            split3(w, w0, w1, w2s);
            Bf[0][ct][j] = (short)w0;
            Bf[1][ct][j] = (short)w1;
            Bf[2][ct][j] = (short)w2s;
        }
    }
    const float tb2v = tb2[0];

    // ====== phase 1: fc1 via MFMA (direct global A-fragments) + gelu + fc2 ==
    const long rowBase = bw * Cn;              // 832 rows per wave
    #pragma unroll 1
    for (int si = 0; si < 26; ++si) {
        #pragma unroll
        for (int tt = 0; tt < 2; ++tt) {
            const float* xr =
                ctx + (rowBase + si * 32 + tt * 16 + col) * (long)Tn + koff;
            float4 xa = *reinterpret_cast<const float4*>(xr);
            float4 xb = *reinterpret_cast<const float4*>(xr + 4);

            union { unsigned w[4]; bf16x8 v; } F0, F1, F2;
            split_pair(xa.x, xa.y, F0.w[0], F1.w[0], F2.w[0]);
            split_pair(xa.z, xa.w, F0.w[1], F1.w[1], F2.w[1]);
            split_pair(xb.x, xb.y, F0.w[2], F1.w[2], F2.w[2]);
            split_pair(xb.z, xb.w, F0.w[3], F1.w[3], F2.w[3]);
            bf16x8 Af0 = F0.v, Af1 = F1.v, Af2 = F2.v;

            f32x4 acc[4];
            #pragma unroll
            for (int ct = 0; ct < 4; ++ct)
                acc[ct] = (f32x4){ biasv[ct], biasv[ct], biasv[ct], biasv[ct] };

            #pragma unroll
            for (int ct = 0; ct < 4; ++ct) {
                acc[ct] = __builtin_amdgcn_mfma_f32_16x16x32_bf16(Af0, Bf[0][ct], acc[ct], 0, 0, 0);
                acc[ct] = __builtin_amdgcn_mfma_f32_16x16x32_bf16(Af0, Bf[1][ct], acc[ct], 0, 0, 0);
                acc[ct] = __builtin_amdgcn_mfma_f32_16x16x32_bf16(Af1, Bf[0][ct], acc[ct], 0, 0, 0);
                acc[ct] = __builtin_amdgcn_mfma_f32_16x16x32_bf16(Af1, Bf[1][ct], acc[ct], 0, 0, 0);
                acc[ct] = __builtin_amdgcn_mfma_f32_16x16x32_bf16(Af0, Bf[2][ct], acc[ct], 0, 0, 0);
                acc[ct] = __builtin_amdgcn_mfma_f32_16x16x32_bf16(Af2, Bf[0][ct], acc[ct], 0, 0, 0);
            }

            // gelu + fc2 partials (C/D: col=l&15, row=kgrp*4+reg)
            float p0 = 0.0f, p1 = 0.0f, p2 = 0.0f, p3 = 0.0f;
            #pragma unroll
            for (int ct = 0; ct < 4; ++ct) {
                p0 = fmaf(fast_gelu(acc[ct][0]), w2v[ct], p0);
                p1 = fmaf(fast_gelu(acc[ct][1]), w2v[ct], p1);
                p2 = fmaf(fast_gelu(acc[ct][2]), w2v[ct], p2);
                p3 = fmaf(fast_gelu(acc[ct][3]), w2v[ct], p3);
            }
            p0 = dpp_reduce16(p0);
            p1 = dpp_reduce16(p1);
            p2 = dpp_reduce16(p2);
            p3 = dpp_reduce16(p3);
            if (col < 4) {   // 16 writer lanes -> 16 rows of this tile
                float val = (col & 1) ? ((col & 2) ? p3 : p1)
                                      : ((col & 2) ? p2 : p0);
                tv[wid][si * 32 + tt * 16 + kgrp * 4 + col] = val + tb2v;
            }
        }
    }

    __syncthreads();   // cross-lane tv handoff (single barrier in kernel)

    // ================= phase 2: per-b c_mlp + gumbel + softmax + topk =======
    const long b = bw + l;

    float t13[Cn];
    #pragma unroll
    for (int c = 0; c < Cn; ++c) t13[c] = tv[wid][l * Cn + c];

    float logits[En];
    #pragma unroll
    for (int e = 0; e < En; ++e) logits[e] = cb2[e];

    #pragma unroll 1
    for (int h = 0; h < Hn; ++h) {
        float a = cb1[h];
        #pragma unroll
        for (int c = 0; c < Cn; ++c)
            a = fmaf(t13[c], cw1[c * Hn + h], a);
        float gg = fast_gelu(a);
        #pragma unroll
        for (int e = 0; e < En; ++e)
            logits[e] = fmaf(gg, cw2[h * En + e], logits[e]);
    }

    // gumbel (custom fp64 logs), y = logits + g
    const float4* up = reinterpret_cast<const float4*>(u + b * En);
    float4 u0 = up[0], u1 = up[1];
    float uv[En] = { u0.x, u0.y, u0.z, u0.w, u1.x, u1.y, u1.z, u1.w };

    double y[En];
    #pragma unroll
    for (int e = 0; e < En; ++e) {
        double w = -fast_log((double)uv[e]);
        y[e] = (double)logits[e] - fast_log(w + 1e-10);   // tau = 1
    }

    // softmax in fp32 (probs compared at bf16 tolerance)
    double m = y[0];
    #pragma unroll
    for (int e = 1; e < En; ++e) m = fmax(m, y[e]);
    float p[En], s = 0.0f;
    #pragma unroll
    for (int e = 0; e < En; ++e) {
        p[e] = EXP2F((float)(y[e] - m) * 1.4426950408889634f);
        s += p[e];
    }
    float inv = RCPF(s);

    // top-3 on y (fp64 ordering == probs ordering), bitmask
    unsigned sel = 0u;
    #pragma unroll
    for (int k = 0; k < Kn; ++k) {
        int best = 0;
        double bv = -1.0e300;
        #pragma unroll
        for (int e = 0; e < En; ++e) {
            bool ok = (((sel >> e) & 1u) == 0u) && (y[e] > bv);
            bv = ok ? y[e] : bv;
            best = ok ? e : best;
        }
        sel |= (1u << best);
    }

    // stores
    float4* om = reinterpret_cast<float4*>(out + b * En);
    om[0] = make_float4((sel >> 0) & 1u, (sel >> 1) & 1u,
                        (sel >> 2) & 1u, (sel >> 3) & 1u);
    om[1] = make_float4((sel >> 4) & 1u, (sel >> 5) & 1u,
                        (sel >> 6) & 1u, (sel >> 7) & 1u);
    float4* op = reinterpret_cast<float4*>(out + (long)Bn * En + b * En);
    op[0] = make_float4(p[0] * inv, p[1] * inv, p[2] * inv, p[3] * inv);
    op[1] = make_float4(p[4] * inv, p[5] * inv, p[6] * inv, p[7] * inv);
}

extern "C" void kernel_launch(void* const* d_in, const int* in_sizes, int n_in,
                              void* d_out, int out_size, void* d_ws, size_t ws_size,
                              hipStream_t stream) {
    const float* ctx = (const float*)d_in[0];
    const float* u   = (const float*)d_in[1];
    const float* tw1 = (const float*)d_in[2];
    const float* tb1 = (const float*)d_in[3];
    const float* tw2 = (const float*)d_in[4];
    const float* tb2 = (const float*)d_in[5];
    const float* cw1 = (const float*)d_in[6];
    const float* cb1 = (const float*)d_in[7];
    const float* cw2 = (const float*)d_in[8];
    const float* cb2 = (const float*)d_in[9];
    float* out = (float*)d_out;

    dim3 grid(Bn / 256), block(256);
    router_kernel<<<grid, block, 0, stream>>>(ctx, u, tw1, tb1, tw2, tb2,
                                              cw1, cb1, cw2, cb2, out);
}